// Round 13
// baseline (188.598 us; speedup 1.0000x reference)
//
#include <hip/hip_runtime.h>
#include <stdint.h>

typedef __attribute__((ext_vector_type(4)))  float  float4v;
typedef __attribute__((ext_vector_type(16))) float  f32x16;
typedef __attribute__((ext_vector_type(8)))  __bf16 bf16x8;
typedef __attribute__((ext_vector_type(8)))  unsigned short ushort8;

#define B_DIM 8192
#define H_DIM 1024
#define O_DIM 1024

static __device__ __forceinline__ unsigned short f32_to_bf16(float f) {
  union { float f; unsigned int u; } v; v.f = f;
  unsigned int u = v.u;
  unsigned int r = u + 0x7FFFu + ((u >> 16) & 1u);  // round-to-nearest-even
  return (unsigned short)(r >> 16);
}

// ---------------------------------------------------------------------------
// prep_inputs: unchanged (near memory floor).
// ---------------------------------------------------------------------------
__global__ void prep_inputs(const float* __restrict__ state,
                            const float* __restrict__ basis,
                            const float* __restrict__ prjw,
                            unsigned short* __restrict__ Abf,
                            unsigned short* __restrict__ Wt) {
  __shared__ __align__(16) unsigned short t[64 * 72];
  int bb = blockIdx.x;
  int tid = threadIdx.x;
  if (bb < 1280) {
    int m = bb >> 8, panel = bb & 255;
    int o0 = (panel & 15) * 64, h0 = (panel >> 4) * 64;
    const float* src = (m < 4) ? (basis + (size_t)m * H_DIM * O_DIM) : prjw;  // [H][O]
    int r  = tid >> 4;
    int c4 = (tid & 15) * 4;
#pragma unroll
    for (int p = 0; p < 4; ++p) {
      int h = r + p * 16;
      float4v v = *(const float4v*)(src + (size_t)(h0 + h) * O_DIM + o0 + c4);
      t[(c4 + 0) * 72 + h] = f32_to_bf16(v.x);
      t[(c4 + 1) * 72 + h] = f32_to_bf16(v.y);
      t[(c4 + 2) * 72 + h] = f32_to_bf16(v.z);
      t[(c4 + 3) * 72 + h] = f32_to_bf16(v.w);
    }
    __syncthreads();
#pragma unroll
    for (int i = 0; i < 2; ++i) {
      int C = i * 256 + tid;
      int o = C >> 3, cc = C & 7;
      ushort8 val = *(const ushort8*)(t + o * 72 + cc * 8);
      *(ushort8*)(Wt + ((size_t)m * O_DIM + o0 + o) * H_DIM + h0 + cc * 8) = val;
    }
  } else {
    int i = (bb - 1280) * 256 + tid;  // 8 elems per thread
    float4v v0 = ((const float4v*)state)[i * 2];
    float4v v1 = ((const float4v*)state)[i * 2 + 1];
    ushort8 o;
    o[0] = f32_to_bf16(v0.x); o[1] = f32_to_bf16(v0.y);
    o[2] = f32_to_bf16(v0.z); o[3] = f32_to_bf16(v0.w);
    o[4] = f32_to_bf16(v1.x); o[5] = f32_to_bf16(v1.y);
    o[6] = f32_to_bf16(v1.z); o[7] = f32_to_bf16(v1.w);
    ((ushort8*)Abf)[i] = o;
  }
}

// ---------------------------------------------------------------------------
// R13 = R9 skeleton (verified 82us) with 32x32x16 MFMA instead of 16x16x32.
//  Why: all schedules land at ~3080 cyc/stage = LDS(1790) + matrix(1552)
//  sum; R4 (2 independent blocks/CU) also serialized -> shared LDS BW +
//  RF-port contention, not barriers.  32x32x16: same LDS bytes/frags, but
//  20 MFMA/stage instead of 40, matrix 1552->1291 cyc (2382 vs 2075 TF
//  ubench), 37% less RF traffic per FLOP.  Acc = 2 x f32x16 per mode (160
//  regs, unchanged).  Frag maps: A row=lane&31, k=8*(lane>>5)+e (per-ks
//  chunk = ks*2+(lane>>5)); B col=lane&31 same form.  C/D: col=lane&31,
//  row=(reg&3)+8*(reg>>2)+4*(lane>>5)  [m74/m101-verified].
//  Ring/vmcnt/barrier machinery byte-identical to R9.
// ---------------------------------------------------------------------------
__global__ __launch_bounds__(512, 2)
void gemm_fused(const unsigned short* __restrict__ A,
                const unsigned short* __restrict__ Wt,
                const float* __restrict__ se, const float* __restrict__ curv,
                const float* __restrict__ gw, const float* __restrict__ gb,
                const float* __restrict__ prjb,
                float* __restrict__ out) {
  __shared__ __align__(16) unsigned char smem[115712];  // 3*36864 + 5120 (scf)
  float* scf = (float*)(smem + 110592);  // 5 x 256 fp32 = 5120 B

  const int tid  = threadIdx.x;
  const int lane = tid & 63;
  const int wave = tid >> 6;
  const int row0 = blockIdx.x * 256;
  const int col0 = blockIdx.y * 64;
  const int wrow = (wave >> 1) * 64;   // 0,64,128,192
  const int wcol = (wave & 1) * 32;    // 0 or 32
  const int l31 = lane & 31;
  const int lh  = lane >> 5;           // 0 or 1 (k-group)

  // ---- staging descriptors (identical to R9).  1KB chunk = 16 rows x 32k.
  const unsigned short* gsrc[5];
  unsigned int ldsoff[5];
  if (wave < 4) {
#pragma unroll
    for (int j = 0; j < 4; ++j) {
      int c = wave * 4 + j;                 // A chunk 0..15
      int row = c * 16 + (lane >> 2);
      int pos = lane & 3;
      int g = pos ^ ((row >> 1) & 3);
      gsrc[j] = A + (size_t)(row0 + row) * H_DIM + g * 8;
      ldsoff[j] = c * 1024;
    }
    gsrc[4] = gsrc[0]; ldsoff[4] = ldsoff[0];  // never issued for A-waves
  } else {
#pragma unroll
    for (int j = 0; j < 5; ++j) {
      int c = (wave - 4) * 5 + j;           // B chunk 0..19
      int m = c >> 2;                       // mode (4 chunks per mode)
      int r = (c & 3) * 16 + (lane >> 2);   // row within mode slab (0..63)
      int pos = lane & 3;
      int g = pos ^ ((r >> 1) & 3);
      gsrc[j] = Wt + (size_t)m * O_DIM * H_DIM + (size_t)(col0 + r) * H_DIM + g * 8;
      ldsoff[j] = 16384 + c * 1024;
    }
  }

  // ---- fragment byte offsets for 32x32x16 (ushort units; row = 32 ushorts)
  //  A frag (rt,ks): row = wrow + rt*32 + l31; chunk pos = ks*2 + lh
  int aoff[2][2];
#pragma unroll
  for (int rt = 0; rt < 2; ++rt)
#pragma unroll
    for (int ks = 0; ks < 2; ++ks) {
      int ra = wrow + rt * 32 + l31;
      int g = (ks * 2 + lh) ^ ((ra >> 1) & 3);
      aoff[rt][ks] = ra * 32 + g * 8;
    }
  //  B frag (ks): col rb = wcol + l31; chunk pos = ks*2 + lh
  int boff[2];
#pragma unroll
  for (int ks = 0; ks < 2; ++ks) {
    int rb = wcol + l31;
    int g = (ks * 2 + lh) ^ ((rb >> 1) & 3);
    boff[ks] = rb * 32 + g * 8;
  }

  f32x16 acc[5][2];
#pragma unroll
  for (int m = 0; m < 5; ++m)
#pragma unroll
    for (int rt = 0; rt < 2; ++rt)
#pragma unroll
      for (int r = 0; r < 16; ++r)
        acc[m][rt][r] = 0.f;

#define ISSUE_SLOT(boff_)                                                       \
  do {                                                                          \
    unsigned char* _dst = smem + (boff_);                                       \
    __builtin_amdgcn_global_load_lds(                                           \
        (const __attribute__((address_space(1))) void*)gsrc[0],                 \
        (__attribute__((address_space(3))) void*)(_dst + ldsoff[0]), 16, 0, 0); \
    __builtin_amdgcn_global_load_lds(                                           \
        (const __attribute__((address_space(1))) void*)gsrc[1],                 \
        (__attribute__((address_space(3))) void*)(_dst + ldsoff[1]), 16, 0, 0); \
    __builtin_amdgcn_global_load_lds(                                           \
        (const __attribute__((address_space(1))) void*)gsrc[2],                 \
        (__attribute__((address_space(3))) void*)(_dst + ldsoff[2]), 16, 0, 0); \
    __builtin_amdgcn_global_load_lds(                                           \
        (const __attribute__((address_space(1))) void*)gsrc[3],                 \
        (__attribute__((address_space(3))) void*)(_dst + ldsoff[3]), 16, 0, 0); \
    if (wave >= 4)                                                              \
      __builtin_amdgcn_global_load_lds(                                         \
          (const __attribute__((address_space(1))) void*)gsrc[4],               \
          (__attribute__((address_space(3))) void*)(_dst + ldsoff[4]), 16, 0, 0);\
    _Pragma("unroll") for (int _j = 0; _j < 5; ++_j) gsrc[_j] += 32;            \
  } while (0)

#define WAITL                                                                   \
  do { if (wave < 4) asm volatile("s_waitcnt vmcnt(4)" ::: "memory");           \
       else          asm volatile("s_waitcnt vmcnt(5)" ::: "memory"); } while (0)

  // persistent ph0 fragments (A x4; modes 0,1 B x4), carried across barrier
  bf16x8 a00, a01, a10, a11, m0k0, m0k1, m1k0, m1k1;

#define READ_PH0(boff_)                                                         \
  do {                                                                          \
    const unsigned short* _sA = (const unsigned short*)(smem + (boff_));        \
    const unsigned short* _sB = _sA + 8192;                                     \
    a00 = *(const bf16x8*)(_sA + aoff[0][0]);                                   \
    a01 = *(const bf16x8*)(_sA + aoff[0][1]);                                   \
    a10 = *(const bf16x8*)(_sA + aoff[1][0]);                                   \
    a11 = *(const bf16x8*)(_sA + aoff[1][1]);                                   \
    m0k0 = *(const bf16x8*)(_sB + boff[0]);                                     \
    m0k1 = *(const bf16x8*)(_sB + boff[1]);                                     \
    m1k0 = *(const bf16x8*)(_sB + 2048 + boff[0]);                              \
    m1k1 = *(const bf16x8*)(_sB + 2048 + boff[1]);                              \
  } while (0)

// 4 MFMAs per mode: (rt 0,1) x (ks 0,1), ks accumulates into same acc.
#define MFMA_MODE(m_, bk0, bk1)                                                 \
  do {                                                                          \
    acc[m_][0] = __builtin_amdgcn_mfma_f32_32x32x16_bf16(a00, bk0, acc[m_][0], 0, 0, 0); \
    acc[m_][1] = __builtin_amdgcn_mfma_f32_32x32x16_bf16(a10, bk0, acc[m_][1], 0, 0, 0); \
    acc[m_][0] = __builtin_amdgcn_mfma_f32_32x32x16_bf16(a01, bk1, acc[m_][0], 0, 0, 0); \
    acc[m_][1] = __builtin_amdgcn_mfma_f32_32x32x16_bf16(a11, bk1, acc[m_][1], 0, 0, 0); \
  } while (0)

// B region of a slot = ushort offset 8192.  Mode m at +m*2048 ushorts.
#define PH1_READS(boff_)                                                        \
  const unsigned short* _cB = (const unsigned short*)(smem + (boff_)) + 8192;   \
  bf16x8 c2k0 = *(const bf16x8*)(_cB + 2 * 2048 + boff[0]);                     \
  bf16x8 c2k1 = *(const bf16x8*)(_cB + 2 * 2048 + boff[1]);                     \
  bf16x8 c3k0 = *(const bf16x8*)(_cB + 3 * 2048 + boff[0]);                     \
  bf16x8 c3k1 = *(const bf16x8*)(_cB + 3 * 2048 + boff[1]);                     \
  bf16x8 c4k0 = *(const bf16x8*)(_cB + 4 * 2048 + boff[0]);                     \
  bf16x8 c4k1 = *(const bf16x8*)(_cB + 4 * 2048 + boff[1])

#define MFMA_ALL5                                                               \
  do {                                                                          \
    __builtin_amdgcn_s_setprio(1);                                              \
    MFMA_MODE(0, m0k0, m0k1);                                                   \
    MFMA_MODE(1, m1k0, m1k1);                                                   \
    MFMA_MODE(2, c2k0, c2k1);                                                   \
    MFMA_MODE(3, c3k0, c3k1);                                                   \
    MFMA_MODE(4, c4k0, c4k1);                                                   \
    __builtin_amdgcn_s_setprio(0);                                              \
  } while (0)

  // ---- prologue: fill slots 0,1 (stages 0,1); scf prep overlaps DMA
  ISSUE_SLOT(0u);
  ISSUE_SLOT(36864u);
  if (tid < 256) {
    int b = row0 + tid;
    float s = se[b];
    float l0 = fmaf(s, gw[0], gb[0]);
    float l1 = fmaf(s, gw[1], gb[1]);
    float l2 = fmaf(s, gw[2], gb[2]);
    float l3 = fmaf(s, gw[3], gb[3]);
    float mx = fmaxf(fmaxf(l0, l1), fmaxf(l2, l3));
    float e0 = __expf(l0 - mx), e1 = __expf(l1 - mx);
    float e2 = __expf(l2 - mx), e3 = __expf(l3 - mx);
    float mix = 1.0f / (1.0f + __expf(-curv[b]));
    float inv = mix / (e0 + e1 + e2 + e3);
    scf[0 * 256 + tid] = e0 * inv;
    scf[1 * 256 + tid] = e1 * inv;
    scf[2 * 256 + tid] = e2 * inv;
    scf[3 * 256 + tid] = e3 * inv;
    scf[4 * 256 + tid] = 1.0f - mix;
  }
  WAITL;                               // stage 0 landed (own wave); stage 1 in flight
  __builtin_amdgcn_s_barrier();        // all waves: stage 0 ready
  __builtin_amdgcn_sched_barrier(0);
  READ_PH0(0u);

  // ---- main loop: stages 0..29 (uniform body), tail 30,31
  unsigned int cS = 0u, nS = 36864u, iS = 73728u;
#pragma unroll 1
  for (int s = 0; s < 30; ++s) {
    ISSUE_SLOT(iS);                    // stage s+2 into the freed slot
    PH1_READS(cS);                     // modes 2-4 frags of stage s
    MFMA_ALL5;                         // ph0 carried + ph1 (counted lgkmcnt)
    WAITL;                             // stage s+1 landed (own wave); s+2 in flight
    __builtin_amdgcn_s_barrier();      // all waves: stage s+1 ready
    __builtin_amdgcn_sched_barrier(0);
    READ_PH0(nS);                      // ph0 frags of stage s+1
    unsigned int t_ = cS; cS = nS; nS = iS; iS = t_;
  }
  // tail: stage 30 (no issue; drain for stage 31), stage 31
  {
    PH1_READS(cS);
    MFMA_ALL5;
    asm volatile("s_waitcnt vmcnt(0)" ::: "memory");  // stage 31 landed
    __builtin_amdgcn_s_barrier();
    __builtin_amdgcn_sched_barrier(0);
    READ_PH0(nS);
  }
  {
    PH1_READS(nS);
    MFMA_ALL5;
  }

  // ---- epilogue: mode-combine -> LDS repack (fp32, pitch 68) -> float4 stores
  //  32x32 C/D map: col = lane&31, row = (reg&3) + 8*(reg>>2) + 4*(lane>>5)
  __syncthreads();
  float* fbuf = (float*)smem;  // 256 x 68 fp32 = 69632 B (scf at 110592 safe)
  {
    int cc = wcol + l31;
#pragma unroll
    for (int rt = 0; rt < 2; ++rt) {
      int rbase = wrow + rt * 32 + 4 * lh;
#pragma unroll
      for (int r = 0; r < 16; ++r) {
        int row = rbase + (r & 3) + 8 * (r >> 2);
        float v = 0.f;
#pragma unroll
        for (int m = 0; m < 5; ++m)
          v += scf[m * 256 + row] * acc[m][rt][r];
        fbuf[row * 68 + cc] = v;
      }
    }
  }
  __syncthreads();
#pragma unroll
  for (int i = 0; i < 8; ++i) {
    int L = i * 512 + tid;          // 4096 float4s = 256 rows x 16
    int row = L >> 4, c4 = L & 15;
    float4v v = *(const float4v*)(fbuf + row * 68 + c4 * 4);
    float cb = scf[4 * 256 + row];
    float4v pb = *(const float4v*)(prjb + col0 + c4 * 4);
    v += cb * pb;
    *(float4v*)(out + (size_t)(row0 + row) * O_DIM + col0 + c4 * 4) = v;
  }
#undef ISSUE_SLOT
#undef WAITL
#undef READ_PH0
#undef MFMA_MODE
#undef PH1_READS
#undef MFMA_ALL5
}

// ---------------------------------------------------------------------------
extern "C" void kernel_launch(void* const* d_in, const int* in_sizes, int n_in,
                              void* d_out, int out_size, void* d_ws, size_t ws_size,
                              hipStream_t stream) {
  const float* state = (const float*)d_in[0];
  const float* se    = (const float*)d_in[1];
  const float* curv  = (const float*)d_in[2];
  const float* basis = (const float*)d_in[3];
  const float* gw    = (const float*)d_in[4];
  const float* gb    = (const float*)d_in[5];
  const float* prjw  = (const float*)d_in[6];
  const float* prjb  = (const float*)d_in[7];
  float* out = (float*)d_out;

  char* ws = (char*)d_ws;
  unsigned short* Abf = (unsigned short*)ws;                               // 16 MB
  unsigned short* Wt  = (unsigned short*)(ws + (size_t)16 * 1024 * 1024);  // 10 MB

  prep_inputs<<<5376, 256, 0, stream>>>(state, basis, prjw, Abf, Wt);
  dim3 gg(B_DIM / 256, O_DIM / 64);
  gemm_fused<<<gg, 512, 0, stream>>>(Abf, Wt, se, curv, gw, gb, prjb, out);
}